// Round 1
// baseline (134.160 us; speedup 1.0000x reference)
//
#include <hip/hip_runtime.h>
#include <math.h>

#define N_FZ    60
#define N_KEZ   20
#define N_TINT  30
#define N_ALPHA 200
#define NORB    2000
#define NTIMES  1000
#define BLOCK   256

// Block = one time index t. Slab grid[fZ0[t], kEZ_ind] staged in LDS as
// adjacent-pair float2 so g0/g1 come from a single ds_read_b64.
__global__ __launch_bounds__(BLOCK) void pdet_kernel(
    const float* __restrict__ alpha,      // (NORB, NTIMES)
    const float* __restrict__ dMag,       // (NORB, NTIMES)
    const float* __restrict__ fZ_vals,    // (NTIMES,)
    const float* __restrict__ kEZ_val,    // scalar
    const float* __restrict__ grid,       // (N_FZ, N_KEZ, N_TINT, N_ALPHA)
    const float* __restrict__ kEZs,       // (N_KEZ,)
    const float* __restrict__ alphas,     // (N_ALPHA,)
    const float* __restrict__ log_fZs,    // (N_FZ,)
    const float* __restrict__ log_alphas, // (N_ALPHA,)
    float* __restrict__ out)              // (NTIMES, N_TINT)
{
    __shared__ float2 pairs[N_TINT * N_ALPHA];   // 48000 B
    __shared__ int    wsum[BLOCK / 64][N_TINT];  // 480 B

    const int t   = blockIdx.x;
    const int tid = threadIdx.x;

    // ---- scalar parameters (uniform; compiler scalarizes) ----
    const float la0    = log_alphas[0];
    const float inv_la = 1.0f / (log_alphas[1] - la0);
    const float alo    = alphas[0];
    const float ahi    = alphas[N_ALPHA - 1];

    // fZ0 for this t: floor(fZ_ind)+1 clipped to [0, N_FZ-2].
    // Index computed in double to minimize boundary disagreement with np.
    const float lf0    = log_fZs[0];
    const float lfstep = log_fZs[1] - lf0;
    double fZ_ind = (log10((double)fZ_vals[t]) - (double)lf0) * (1.0 / (double)lfstep);
    int fZ0 = (int)floor(fZ_ind) + 1;
    fZ0 = min(max(fZ0, 0), N_FZ - 2);

    // kEZ index: searchsorted(kEZs, kEZ_val, 'right') - 1 (emulate negative wrap)
    const float kv = kEZ_val[0];
    int kidx = -1;
    #pragma unroll
    for (int i = 0; i < N_KEZ; ++i) kidx += (kEZs[i] <= kv) ? 1 : 0;
    if (kidx < 0) kidx += N_KEZ;

    // ---- stage pair-slab into LDS ----
    const float* src = grid + ((size_t)fZ0 * N_KEZ + kidx) * (N_TINT * N_ALPHA);
    const float4* src4 = (const float4*)src;
    for (int j = tid; j < (N_TINT * N_ALPHA) / 4; j += BLOCK) {
        float4 v  = src4[j];
        float nxt = src[4 * j + 4];   // safe: next element exists within grid
        pairs[4 * j + 0] = make_float2(v.x, v.y);
        pairs[4 * j + 1] = make_float2(v.y, v.z);
        pairs[4 * j + 2] = make_float2(v.z, v.w);
        pairs[4 * j + 3] = make_float2(v.w, nxt);
    }
    __syncthreads();

    int cnt[N_TINT];
    #pragma unroll
    for (int k = 0; k < N_TINT; ++k) cnt[k] = 0;

    for (int orb = tid; orb < NORB; orb += BLOCK) {
        float a  = alpha[(size_t)orb * NTIMES + t];
        float dm = dMag [(size_t)orb * NTIMES + t];
        bool geom = (a >= alo) && (a <= ahi);
        float a_ind = (log10f(a) - la0) * inv_la;
        int a0 = (int)a_ind;                       // trunc toward zero
        a0 = min(max(a0, 0), N_ALPHA - 1);
        float dal = a_ind - (float)a0;             // may be <0 or >1 when clipped (masked anyway)
        int a0s = min(a0, N_ALPHA - 2);
        if (!geom) dm = __builtin_inff();          // geom_mask=false -> never detected

        #pragma unroll
        for (int k = 0; k < N_TINT; ++k) {
            float2 p = pairs[k * N_ALPHA + a0s];
            float dim = p.x + dal * (p.y - p.x);
            cnt[k] += (dm < dim) ? 1 : 0;
        }
    }

    // ---- reduction: wave shfl_xor, then cross-wave via LDS ----
    const int lane = tid & 63;
    const int wid  = tid >> 6;
    #pragma unroll
    for (int k = 0; k < N_TINT; ++k) {
        int c = cnt[k];
        c += __shfl_xor(c, 32, 64);
        c += __shfl_xor(c, 16, 64);
        c += __shfl_xor(c,  8, 64);
        c += __shfl_xor(c,  4, 64);
        c += __shfl_xor(c,  2, 64);
        c += __shfl_xor(c,  1, 64);
        if (lane == 0) wsum[wid][k] = c;
    }
    __syncthreads();

    if (tid < N_TINT) {
        int tot = wsum[0][tid] + wsum[1][tid] + wsum[2][tid] + wsum[3][tid];
        out[(size_t)t * N_TINT + tid] = (float)tot / (float)NORB;
    }
}

extern "C" void kernel_launch(void* const* d_in, const int* in_sizes, int n_in,
                              void* d_out, int out_size, void* d_ws, size_t ws_size,
                              hipStream_t stream) {
    const float* alpha      = (const float*)d_in[0];
    const float* dMag       = (const float*)d_in[1];
    const float* fZ_vals    = (const float*)d_in[2];
    const float* kEZ_val    = (const float*)d_in[3];
    const float* grid       = (const float*)d_in[4];
    const float* kEZs       = (const float*)d_in[5];
    const float* alphas     = (const float*)d_in[6];
    const float* log_fZs    = (const float*)d_in[7];
    const float* log_alphas = (const float*)d_in[8];
    float* out = (float*)d_out;

    pdet_kernel<<<NTIMES, BLOCK, 0, stream>>>(
        alpha, dMag, fZ_vals, kEZ_val, grid, kEZs, alphas, log_fZs, log_alphas, out);
}